// Round 11
// baseline (56.796 us; speedup 1.0000x reference)
//
#include <hip/hip_runtime.h>
#include <cmath>

#define BN 8192
#define DIM 128
#define MARGIN_F 0.3f
#define NRB 64                    // 128-row blocks
#define NTILE (NRB * (NRB + 1) / 2)   // 2080 upper-tri tiles
#define IMAX 0x7FFFFFFF
#define IMIN 0x80000000

typedef __attribute__((ext_vector_type(4))) int i32x4;

__device__ __forceinline__ int imin3(int a, int b, int c) { return min(a, min(b, c)); }
__device__ __forceinline__ int imax3(int a, int b, int c) { return max(a, max(b, c)); }

// ---------------- K1: fp32 row norms -> sqv + k-major i8 quantized copy ----------------
// Also: LP packed column-label table (LP[cb*16+lrow] = 4 label bytes of cols
// cb*64 + {0,16,32,48} + lrow; 128 groups, 8 KB, L2-resident) and ap_f/an_f
// sentinel seeding for K2's atomic merge.
__global__ __launch_bounds__(256) void norm_cvt_k(
    const float* __restrict__ emb, const int* __restrict__ lab,
    float* __restrict__ sqv, unsigned short* __restrict__ EnQ16,
    unsigned* __restrict__ LP, int* __restrict__ ap_f, int* __restrict__ an_f)
{
  int gt = blockIdx.x * blockDim.x + threadIdx.x;
  if (gt < BN) { ap_f[gt] = IMAX; an_f[gt] = IMIN; }
  if (gt < 2048) {
    int base = (gt >> 4) * 64 + (gt & 15);
    LP[gt] = (unsigned)(lab[base] & 255) | ((unsigned)(lab[base + 16] & 255) << 8) |
             ((unsigned)(lab[base + 32] & 255) << 16) | ((unsigned)(lab[base + 48] & 255) << 24);
  }

  int w = gt >> 6;  // one wave per row
  int lane = threadIdx.x & 63;
  if (w >= BN) return;
  float2 v = *reinterpret_cast<const float2*>(&emb[w * DIM + lane * 2]);
  float s = v.x * v.x + v.y * v.y;
  #pragma unroll
  for (int off = 32; off > 0; off >>= 1) s += __shfl_xor(s, off);
  float iv = 1.0f / fmaxf(sqrtf(s), 1e-12f);
  if (lane == 0) sqv[w] = s * iv * iv;
  int q0 = (int)rintf(127.0f * v.x * iv);
  int q1 = (int)rintf(127.0f * v.y * iv);
  unsigned short us = (unsigned short)((q0 & 255) | ((q1 & 255) << 8));
  int g = lane >> 3;                                  // k = 2*lane -> chunk g = lane/8
  EnQ16[(g * BN + w) * 8 + (lane & 7)] = us;
}

// ---------------- K2: upper-triangular i8-MFMA gram + two-sided hard mining ----------------
// dot(i,j)=dot(j,i): compute only tiles (R,C) with C>=R (2080 of 4096 = 0.508x the
// MFMA/B-load work). Each off-diag tile mines BOTH sides: row-side ap/an (as before)
// and col-side via cmin/cmax[4] per lane, reusing the same label predicate and
// selected p/q values (+4 VALU per (mi,r) on 0.5x the tiles -> ~0.75x mining).
// Coverage: j>i via row-side, j<i via col-side, same-block via diag row-mining
// (diag skips col-side: redundant, and min/max is idempotent anyway). Merge via
// device-scope atomicMin/Max (exact for ints, r4-proven). One 128x128 tile per
// block, grid=2080 (~4 generations/CU -> load-balanced). B direct from L2 (r8).
__global__ __launch_bounds__(256, 2) void tri_gram_mine_k(
    const char* __restrict__ EnQ, const int* __restrict__ lab,
    const unsigned* __restrict__ LP,
    int* __restrict__ ap_f, int* __restrict__ an_f)
{
  const int tid = threadIdx.x;
  const int w = tid >> 6, l = tid & 63;
  const int wr = w >> 1, wc = w & 1;
  const int lrow = l & 15, lkg = l >> 4;

  // triangular index -> (R, C), C >= R.  T(r) = r*(129-r)/2 tiles precede row r.
  const int idx = blockIdx.x;
  int R = (int)((129.0f - sqrtf(16641.0f - 8.0f * (float)idx)) * 0.5f);
  while (((R + 1) * (129 - (R + 1))) / 2 <= idx) ++R;   // correction (fp32 rounding)
  while ((R * (129 - R)) / 2 > idx) --R;
  const int C = R + (idx - (R * (129 - R)) / 2);

  const int rowBase = R * 128 + wr * 64;
  const int colBase = C * 128 + wc * 64;
  const bool diagW  = (rowBase == colBase);   // exact-diagonal wave tile
  const bool doCol  = (R != C);               // col-side mining only off block-diag

  // A fragments: 4 row-tiles x 2 K-steps, 16B per frag
  i32x4 a[4][2];
  #pragma unroll
  for (int mi = 0; mi < 4; ++mi)
    #pragma unroll
    for (int kk = 0; kk < 2; ++kk)
      a[mi][kk] = *reinterpret_cast<const i32x4*>(
          EnQ + (((size_t)((kk << 2) + lkg) * BN + rowBase + mi * 16 + lrow) << 4));

  // row labels for the 16 rows this lane owns
  int rlv[4][4];
  #pragma unroll
  for (int mi = 0; mi < 4; ++mi) {
    int rb = rowBase + mi * 16 + lkg * 4;
    #pragma unroll
    for (int r = 0; r < 4; ++r) rlv[mi][r] = lab[rb + r] & 255;
  }

  // packed column labels: one u32 for this wave's 4 col subtiles at lane lrow
  const unsigned LPv = LP[(colBase >> 6) * 16 + lrow];
  const int l0 = (int)(LPv & 255u),         l1 = (int)((LPv >> 8) & 255u);
  const int l2 = (int)((LPv >> 16) & 255u), l3 = (int)(LPv >> 24);

  int ap[4][4], an[4][4];
  #pragma unroll
  for (int mi = 0; mi < 4; ++mi)
    #pragma unroll
    for (int r = 0; r < 4; ++r) { ap[mi][r] = IMAX; an[mi][r] = IMIN; }
  int cmin[4], cmax[4];
  #pragma unroll
  for (int n = 0; n < 4; ++n) { cmin[n] = IMAX; cmax[n] = IMIN; }

  const i32x4 zf = {0, 0, 0, 0};

  // B loads, both halves issued up front (L2 hits; latency hidden under MFMA issue)
  const char* bp0 = EnQ + (((size_t)lkg * BN + colBase + lrow) << 4);
  const char* bp1 = bp0 + ((size_t)BN << 6);   // kk=1 plane (+4*BN*16)

  i32x4 b0[2][2], b1[2][2];
  #pragma unroll
  for (int n = 0; n < 2; ++n) {
    b0[0][n] = *reinterpret_cast<const i32x4*>(bp0 + n * 256);
    b0[1][n] = *reinterpret_cast<const i32x4*>(bp1 + n * 256);
    b1[0][n] = *reinterpret_cast<const i32x4*>(bp0 + (2 + n) * 256);
    b1[1][n] = *reinterpret_cast<const i32x4*>(bp1 + (2 + n) * 256);
  }

  i32x4 accA[4][2], accB[4][2];
  #pragma unroll
  for (int mi = 0; mi < 4; ++mi)
    #pragma unroll
    for (int n = 0; n < 2; ++n)
      accA[mi][n] = __builtin_amdgcn_mfma_i32_16x16x64_i8(a[mi][0], b0[0][n], zf, 0, 0, 0);
  #pragma unroll
  for (int mi = 0; mi < 4; ++mi)
    #pragma unroll
    for (int n = 0; n < 2; ++n)
      accA[mi][n] = __builtin_amdgcn_mfma_i32_16x16x64_i8(a[mi][1], b0[1][n], accA[mi][n], 0, 0, 0);
  #pragma unroll
  for (int mi = 0; mi < 4; ++mi)
    #pragma unroll
    for (int n = 0; n < 2; ++n)
      accB[mi][n] = __builtin_amdgcn_mfma_i32_16x16x64_i8(a[mi][0], b1[0][n], zf, 0, 0, 0);
  #pragma unroll
  for (int mi = 0; mi < 4; ++mi)
    #pragma unroll
    for (int n = 0; n < 2; ++n)
      accB[mi][n] = __builtin_amdgcn_mfma_i32_16x16x64_i8(a[mi][1], b1[1][n], accB[mi][n], 0, 0, 0);

  // mining: three wave-uniform variants (diagW -> no col; doCol -> row+col; else row)
  // refs for col accumulators keep all indexing compile-time (no scratch, rule #20)
  auto mineRow = [&](const i32x4 (&A)[4][2], int la, int lb) {
    #pragma unroll
    for (int mi = 0; mi < 4; ++mi)
      #pragma unroll
      for (int r = 0; r < 4; ++r) {
        int d0 = A[mi][0][r], d1 = A[mi][1][r];
        bool s0 = (rlv[mi][r] == la), s1 = (rlv[mi][r] == lb);
        int p0 = s0 ? d0 : IMAX, p1 = s1 ? d1 : IMAX;
        int q0 = s0 ? IMIN : d0, q1 = s1 ? IMIN : d1;
        ap[mi][r] = imin3(ap[mi][r], p0, p1);
        an[mi][r] = imax3(an[mi][r], q0, q1);
      }
  };
  auto mineRowCol = [&](const i32x4 (&A)[4][2], int la, int lb,
                        int& cmA, int& cxA, int& cmB, int& cxB) {
    #pragma unroll
    for (int mi = 0; mi < 4; ++mi)
      #pragma unroll
      for (int r = 0; r < 4; ++r) {
        int d0 = A[mi][0][r], d1 = A[mi][1][r];
        bool s0 = (rlv[mi][r] == la), s1 = (rlv[mi][r] == lb);
        int p0 = s0 ? d0 : IMAX, p1 = s1 ? d1 : IMAX;
        int q0 = s0 ? IMIN : d0, q1 = s1 ? IMIN : d1;
        ap[mi][r] = imin3(ap[mi][r], p0, p1);
        an[mi][r] = imax3(an[mi][r], q0, q1);
        cmA = min(cmA, p0); cxA = max(cxA, q0);
        cmB = min(cmB, p1); cxB = max(cxB, q1);
      }
  };
  auto mineDiag = [&](const i32x4 (&A)[4][2], int la, int lb, int c0, int c1) {
    #pragma unroll
    for (int mi = 0; mi < 4; ++mi)
      #pragma unroll
      for (int r = 0; r < 4; ++r) {
        int rloc = mi * 16 + lkg * 4 + r;
        int d0 = A[mi][0][r], d1 = A[mi][1][r];
        bool s0 = (rlv[mi][r] == la), s1 = (rlv[mi][r] == lb);
        bool e0 = (rloc == c0), e1 = (rloc == c1);
        int p0 = (s0 && !e0) ? d0 : IMAX, p1 = (s1 && !e1) ? d1 : IMAX;
        int q0 = s0 ? IMIN : d0, q1 = s1 ? IMIN : d1;
        ap[mi][r] = imin3(ap[mi][r], p0, p1);
        an[mi][r] = imax3(an[mi][r], q0, q1);
      }
  };

  if (diagW) {
    mineDiag(accA, l0, l1, lrow, 16 + lrow);
    mineDiag(accB, l2, l3, 32 + lrow, 48 + lrow);
  } else if (doCol) {
    mineRowCol(accA, l0, l1, cmin[0], cmax[0], cmin[1], cmax[1]);
    mineRowCol(accB, l2, l3, cmin[2], cmax[2], cmin[3], cmax[3]);
  } else {   // R==C block, off-diagonal wave tile
    mineRow(accA, l0, l1);
    mineRow(accB, l2, l3);
  }

  // row-side: butterfly across the 16 lrow lanes, then atomics (min side skipped
  // when sentinel — ~1 same-label match per row per 128-col tile on average)
  #pragma unroll
  for (int mi = 0; mi < 4; ++mi)
    #pragma unroll
    for (int r = 0; r < 4; ++r) {
      int p = ap[mi][r], n = an[mi][r];
      #pragma unroll
      for (int off = 1; off < 16; off <<= 1) {
        p = min(p, __shfl_xor(p, off));
        n = max(n, __shfl_xor(n, off));
      }
      if (lrow == 0) {
        int rg = rowBase + mi * 16 + lkg * 4 + r;
        if (p != IMAX) atomicMin(&ap_f[rg], p);
        atomicMax(&an_f[rg], n);
      }
    }

  // col-side: reduce across the 4 lkg lanes sharing each lrow column, then atomics
  if (doCol) {
    #pragma unroll
    for (int n = 0; n < 4; ++n) {
      int cm = cmin[n], cx = cmax[n];
      cm = min(cm, __shfl_xor(cm, 16)); cm = min(cm, __shfl_xor(cm, 32));
      cx = max(cx, __shfl_xor(cx, 16)); cx = max(cx, __shfl_xor(cx, 32));
      if (lkg == 0) {
        int cg = colBase + n * 16 + lrow;
        if (cm != IMAX) atomicMin(&ap_f[cg], cm);
        atomicMax(&an_f[cg], cx);
      }
    }
  }
}

// ---------------- K3: single-block finalize (dispatch acquire publishes K2 atomics) ----------------
__global__ __launch_bounds__(1024) void finalize_k(
    const int* __restrict__ ap_f, const int* __restrict__ an_f,
    const float* __restrict__ sqv, float* __restrict__ out)
{
  int t = threadIdx.x;
  float sum = 0.f, cnt = 0.f;
  #pragma unroll
  for (int i = 0; i < BN / 1024; ++i) {
    int r = i * 1024 + t;
    int apt = ap_f[r], ant = an_f[r];
    if (apt != IMAX && ant != IMIN) {
      const float sc = 2.0f / (127.0f * 127.0f);
      float rs1 = sqv[r] + 1.0f;
      float dap = sqrtf(fmaxf(fmaf(-sc, (float)apt, rs1), 0.f));
      float dan = sqrtf(fmaxf(fmaf(-sc, (float)ant, rs1), 0.f));
      sum += fmaxf(dap - dan + MARGIN_F, 0.f);
      cnt += 1.f;
    }
  }
  #pragma unroll
  for (int off = 32; off > 0; off >>= 1) {
    sum += __shfl_xor(sum, off);
    cnt += __shfl_xor(cnt, off);
  }
  __shared__ float ssum[16], scnt[16];
  int wv = t >> 6;
  if ((t & 63) == 0) { ssum[wv] = sum; scnt[wv] = cnt; }
  __syncthreads();
  if (t == 0) {
    float s = 0.f, c = 0.f;
    #pragma unroll
    for (int i = 0; i < 16; ++i) { s += ssum[i]; c += scnt[i]; }
    out[0] = (c > 0.f) ? (s / c) : 0.f;
  }
}

extern "C" void kernel_launch(void* const* d_in, const int* in_sizes, int n_in,
                              void* d_out, int out_size, void* d_ws, size_t ws_size,
                              hipStream_t stream)
{
  const float* emb = (const float*)d_in[0];
  const int*   lab = (const int*)d_in[1];
  float* out = (float*)d_out;
  float* ws  = (float*)d_ws;

  float*    sqv  = ws;                        // BN floats
  int*      ap_f = (int*)(sqv + BN);          // BN ints
  int*      an_f = ap_f + BN;                 // BN ints
  unsigned* LP   = (unsigned*)(an_f + BN);    // 2048 u32 (8 KB)
  char*     EnQ  = (char*)(LP + 2048);        // BN*DIM i8, k-major (~1 MB)

  norm_cvt_k<<<dim3(BN / 4), 256, 0, stream>>>(emb, lab, sqv, (unsigned short*)EnQ,
                                               LP, ap_f, an_f);
  tri_gram_mine_k<<<dim3(NTILE), 256, 0, stream>>>(EnQ, lab, LP, ap_f, an_f);
  finalize_k<<<dim3(1), 1024, 0, stream>>>(ap_f, an_f, sqv, out);
}

// Round 12
// 38.897 us; speedup vs baseline: 1.4602x; 1.4602x over previous
//
#include <hip/hip_runtime.h>
#include <cmath>

#define BN 8192
#define DIM 128
#define MARGIN_F 0.3f
#define NRB 64                        // 128-row blocks
#define NTILE (NRB * (NRB + 1) / 2)   // 2080 upper-tri tiles
#define NPART 64                      // partial slots per row (exactly the writer count)
#define IMAX 0x7FFFFFFF
#define IMIN 0x80000000

typedef __attribute__((ext_vector_type(4))) int i32x4;

__device__ __forceinline__ int imin3(int a, int b, int c) { return min(a, min(b, c)); }
__device__ __forceinline__ int imax3(int a, int b, int c) { return max(a, max(b, c)); }

// ---------------- K1: fp32 row norms -> sqv + k-major i8 quantized copy ----------------
// Also LP: packed column-label table (LP[cb*16+lrow] = 4 label bytes of cols
// cb*64 + {0,16,32,48} + lrow; 128 groups, 8 KB, L2-resident).
__global__ __launch_bounds__(256) void norm_cvt_k(
    const float* __restrict__ emb, const int* __restrict__ lab,
    float* __restrict__ sqv, unsigned short* __restrict__ EnQ16,
    unsigned* __restrict__ LP)
{
  int gt = blockIdx.x * blockDim.x + threadIdx.x;
  if (gt < 2048) {
    int base = (gt >> 4) * 64 + (gt & 15);
    LP[gt] = (unsigned)(lab[base] & 255) | ((unsigned)(lab[base + 16] & 255) << 8) |
             ((unsigned)(lab[base + 32] & 255) << 16) | ((unsigned)(lab[base + 48] & 255) << 24);
  }

  int w = gt >> 6;  // one wave per row
  int lane = threadIdx.x & 63;
  if (w >= BN) return;
  float2 v = *reinterpret_cast<const float2*>(&emb[w * DIM + lane * 2]);
  float s = v.x * v.x + v.y * v.y;
  #pragma unroll
  for (int off = 32; off > 0; off >>= 1) s += __shfl_xor(s, off);
  float iv = 1.0f / fmaxf(sqrtf(s), 1e-12f);
  if (lane == 0) sqv[w] = s * iv * iv;
  int q0 = (int)rintf(127.0f * v.x * iv);
  int q1 = (int)rintf(127.0f * v.y * iv);
  unsigned short us = (unsigned short)((q0 & 255) | ((q1 & 255) << 8));
  int g = lane >> 3;                                  // k = 2*lane -> chunk g = lane/8
  EnQ16[(g * BN + w) * 8 + (lane & 7)] = us;
}

// ---------------- K2: upper-triangular i8-MFMA gram + two-sided mining, slot partials ----------------
// Triangle (2080 tiles = 0.508x MFMA). r11's atomic merge was the 47us wall
// (17.5 MB memory-side RMW traffic); replaced by DETERMINISTIC SLOT PARTIALS:
// for row-block X the writers are exactly 64 tiles — tile (R,C) row-side -> slot C
// (slots >= R), tile (R',X) col-side -> slot R' (slots < X). Disjoint, each
// (slot,row) cell written exactly once, no init, no atomics; 2 KB coalesced
// stores/block. wc/wr wave halves combined via 4 KB LDS before the store.
__global__ __launch_bounds__(256, 2) void tri_gram_mine_k(
    const char* __restrict__ EnQ, const int* __restrict__ lab,
    const unsigned* __restrict__ LP,
    int* __restrict__ ap_part, int* __restrict__ an_part)
{
  __shared__ int sRP[2][128], sRN[2][128];   // row-side partials, [wc][local row]
  __shared__ int sCP[2][128], sCN[2][128];   // col-side partials, [wr][local col]

  const int tid = threadIdx.x;
  const int w = tid >> 6, l = tid & 63;
  const int wr = w >> 1, wc = w & 1;
  const int lrow = l & 15, lkg = l >> 4;

  // triangular index -> (R, C), C >= R.  T(r) = r*(129-r)/2 tiles precede row r.
  const int idx = blockIdx.x;
  int R = (int)((129.0f - sqrtf(16641.0f - 8.0f * (float)idx)) * 0.5f);
  while (((R + 1) * (129 - (R + 1))) / 2 <= idx) ++R;   // correction (fp32 rounding)
  while ((R * (129 - R)) / 2 > idx) --R;
  const int C = R + (idx - (R * (129 - R)) / 2);

  const int rowBase = R * 128 + wr * 64;
  const int colBase = C * 128 + wc * 64;
  const bool diagW  = (rowBase == colBase);   // exact-diagonal wave tile
  const bool doCol  = (R != C);               // col-side mining only off block-diag

  // A fragments: 4 row-tiles x 2 K-steps, 16B per frag
  i32x4 a[4][2];
  #pragma unroll
  for (int mi = 0; mi < 4; ++mi)
    #pragma unroll
    for (int kk = 0; kk < 2; ++kk)
      a[mi][kk] = *reinterpret_cast<const i32x4*>(
          EnQ + (((size_t)((kk << 2) + lkg) * BN + rowBase + mi * 16 + lrow) << 4));

  // row labels for the 16 rows this lane owns
  int rlv[4][4];
  #pragma unroll
  for (int mi = 0; mi < 4; ++mi) {
    int rb = rowBase + mi * 16 + lkg * 4;
    #pragma unroll
    for (int r = 0; r < 4; ++r) rlv[mi][r] = lab[rb + r] & 255;
  }

  // packed column labels: one u32 for this wave's 4 col subtiles at lane lrow
  const unsigned LPv = LP[(colBase >> 6) * 16 + lrow];
  const int l0 = (int)(LPv & 255u),         l1 = (int)((LPv >> 8) & 255u);
  const int l2 = (int)((LPv >> 16) & 255u), l3 = (int)(LPv >> 24);

  int ap[4][4], an[4][4];
  #pragma unroll
  for (int mi = 0; mi < 4; ++mi)
    #pragma unroll
    for (int r = 0; r < 4; ++r) { ap[mi][r] = IMAX; an[mi][r] = IMIN; }
  int cmin[4], cmax[4];
  #pragma unroll
  for (int n = 0; n < 4; ++n) { cmin[n] = IMAX; cmax[n] = IMIN; }

  const i32x4 zf = {0, 0, 0, 0};

  // B loads, both halves issued up front (L2 hits; latency hidden under MFMA issue)
  const char* bp0 = EnQ + (((size_t)lkg * BN + colBase + lrow) << 4);
  const char* bp1 = bp0 + ((size_t)BN << 6);   // kk=1 plane (+4*BN*16)

  i32x4 b0[2][2], b1[2][2];
  #pragma unroll
  for (int n = 0; n < 2; ++n) {
    b0[0][n] = *reinterpret_cast<const i32x4*>(bp0 + n * 256);
    b0[1][n] = *reinterpret_cast<const i32x4*>(bp1 + n * 256);
    b1[0][n] = *reinterpret_cast<const i32x4*>(bp0 + (2 + n) * 256);
    b1[1][n] = *reinterpret_cast<const i32x4*>(bp1 + (2 + n) * 256);
  }

  i32x4 accA[4][2], accB[4][2];
  #pragma unroll
  for (int mi = 0; mi < 4; ++mi)
    #pragma unroll
    for (int n = 0; n < 2; ++n)
      accA[mi][n] = __builtin_amdgcn_mfma_i32_16x16x64_i8(a[mi][0], b0[0][n], zf, 0, 0, 0);
  #pragma unroll
  for (int mi = 0; mi < 4; ++mi)
    #pragma unroll
    for (int n = 0; n < 2; ++n)
      accA[mi][n] = __builtin_amdgcn_mfma_i32_16x16x64_i8(a[mi][1], b0[1][n], accA[mi][n], 0, 0, 0);
  #pragma unroll
  for (int mi = 0; mi < 4; ++mi)
    #pragma unroll
    for (int n = 0; n < 2; ++n)
      accB[mi][n] = __builtin_amdgcn_mfma_i32_16x16x64_i8(a[mi][0], b1[0][n], zf, 0, 0, 0);
  #pragma unroll
  for (int mi = 0; mi < 4; ++mi)
    #pragma unroll
    for (int n = 0; n < 2; ++n)
      accB[mi][n] = __builtin_amdgcn_mfma_i32_16x16x64_i8(a[mi][1], b1[1][n], accB[mi][n], 0, 0, 0);

  // mining variants (wave-uniform selection); col accumulators passed by ref so
  // all indexing stays compile-time (rule #20, no scratch)
  auto mineRow = [&](const i32x4 (&A)[4][2], int la, int lb) {
    #pragma unroll
    for (int mi = 0; mi < 4; ++mi)
      #pragma unroll
      for (int r = 0; r < 4; ++r) {
        int d0 = A[mi][0][r], d1 = A[mi][1][r];
        bool s0 = (rlv[mi][r] == la), s1 = (rlv[mi][r] == lb);
        int p0 = s0 ? d0 : IMAX, p1 = s1 ? d1 : IMAX;
        int q0 = s0 ? IMIN : d0, q1 = s1 ? IMIN : d1;
        ap[mi][r] = imin3(ap[mi][r], p0, p1);
        an[mi][r] = imax3(an[mi][r], q0, q1);
      }
  };
  auto mineRowCol = [&](const i32x4 (&A)[4][2], int la, int lb,
                        int& cmA, int& cxA, int& cmB, int& cxB) {
    #pragma unroll
    for (int mi = 0; mi < 4; ++mi)
      #pragma unroll
      for (int r = 0; r < 4; ++r) {
        int d0 = A[mi][0][r], d1 = A[mi][1][r];
        bool s0 = (rlv[mi][r] == la), s1 = (rlv[mi][r] == lb);
        int p0 = s0 ? d0 : IMAX, p1 = s1 ? d1 : IMAX;
        int q0 = s0 ? IMIN : d0, q1 = s1 ? IMIN : d1;
        ap[mi][r] = imin3(ap[mi][r], p0, p1);
        an[mi][r] = imax3(an[mi][r], q0, q1);
        cmA = min(cmA, p0); cxA = max(cxA, q0);
        cmB = min(cmB, p1); cxB = max(cxB, q1);
      }
  };
  auto mineDiag = [&](const i32x4 (&A)[4][2], int la, int lb, int c0, int c1) {
    #pragma unroll
    for (int mi = 0; mi < 4; ++mi)
      #pragma unroll
      for (int r = 0; r < 4; ++r) {
        int rloc = mi * 16 + lkg * 4 + r;
        int d0 = A[mi][0][r], d1 = A[mi][1][r];
        bool s0 = (rlv[mi][r] == la), s1 = (rlv[mi][r] == lb);
        bool e0 = (rloc == c0), e1 = (rloc == c1);
        int p0 = (s0 && !e0) ? d0 : IMAX, p1 = (s1 && !e1) ? d1 : IMAX;
        int q0 = s0 ? IMIN : d0, q1 = s1 ? IMIN : d1;
        ap[mi][r] = imin3(ap[mi][r], p0, p1);
        an[mi][r] = imax3(an[mi][r], q0, q1);
      }
  };

  if (diagW) {
    mineDiag(accA, l0, l1, lrow, 16 + lrow);
    mineDiag(accB, l2, l3, 32 + lrow, 48 + lrow);
  } else if (doCol) {
    mineRowCol(accA, l0, l1, cmin[0], cmax[0], cmin[1], cmax[1]);
    mineRowCol(accB, l2, l3, cmin[2], cmax[2], cmin[3], cmax[3]);
  } else {   // R==C block, off-diagonal wave tile
    mineRow(accA, l0, l1);
    mineRow(accB, l2, l3);
  }

  // row-side: butterfly across the 16 lrow lanes, deposit into LDS [wc] plane
  #pragma unroll
  for (int mi = 0; mi < 4; ++mi)
    #pragma unroll
    for (int r = 0; r < 4; ++r) {
      int p = ap[mi][r], n = an[mi][r];
      #pragma unroll
      for (int off = 1; off < 16; off <<= 1) {
        p = min(p, __shfl_xor(p, off));
        n = max(n, __shfl_xor(n, off));
      }
      if (lrow == 0) {
        int rl = wr * 64 + mi * 16 + lkg * 4 + r;
        sRP[wc][rl] = p; sRN[wc][rl] = n;
      }
    }

  // col-side: reduce across the 4 lkg lanes sharing each lrow column, deposit [wr]
  if (doCol) {
    #pragma unroll
    for (int n = 0; n < 4; ++n) {
      int cm = cmin[n], cx = cmax[n];
      cm = min(cm, __shfl_xor(cm, 16)); cm = min(cm, __shfl_xor(cm, 32));
      cx = max(cx, __shfl_xor(cx, 16)); cx = max(cx, __shfl_xor(cx, 32));
      if (lkg == 0) {
        int cl = wc * 64 + n * 16 + lrow;
        sCP[wr][cl] = cm; sCN[wr][cl] = cx;
      }
    }
  }

  __syncthreads();

  // store: row-side partial -> slot C, rows of block R; col-side -> slot R, rows of block C
  const int t = tid & 127;
  if (tid < 128) {
    int p = min(sRP[0][t], sRP[1][t]);
    int n = max(sRN[0][t], sRN[1][t]);
    ap_part[(size_t)C * BN + R * 128 + t] = p;
    an_part[(size_t)C * BN + R * 128 + t] = n;
  } else if (doCol) {
    int p = min(sCP[0][t], sCP[1][t]);
    int n = max(sCN[0][t], sCN[1][t]);
    ap_part[(size_t)R * BN + C * 128 + t] = p;
    an_part[(size_t)R * BN + C * 128 + t] = n;
  }
}

// ---------------- K3a: per-row combine over 64 slots, margin; 64 blocks ----------------
__global__ __launch_bounds__(256) void finalize_a_k(
    const int* __restrict__ ap_part, const int* __restrict__ an_part,
    const float* __restrict__ sqv,
    float* __restrict__ blk_sum, float* __restrict__ blk_cnt)
{
  __shared__ int sP[128], sN[128];
  __shared__ float ssum[4], scnt[4];
  const int tid = threadIdx.x;
  const int t = tid & 127, h = tid >> 7;            // 2 threads per row
  const int r = blockIdx.x * 128 + t;

  int apt = IMAX, ant = IMIN;
  const int s0 = h * 32;
  #pragma unroll 8
  for (int s = 0; s < 32; ++s) {
    apt = min(apt, ap_part[(size_t)(s0 + s) * BN + r]);
    ant = max(ant, an_part[(size_t)(s0 + s) * BN + r]);
  }
  if (h) { sP[t] = apt; sN[t] = ant; }
  __syncthreads();

  float sum = 0.f, cnt = 0.f;
  if (!h) {
    apt = min(apt, sP[t]); ant = max(ant, sN[t]);
    if (apt != IMAX && ant != IMIN) {
      const float sc = 2.0f / (127.0f * 127.0f);
      float rs1 = sqv[r] + 1.0f;
      float dap = sqrtf(fmaxf(fmaf(-sc, (float)apt, rs1), 0.f));
      float dan = sqrtf(fmaxf(fmaf(-sc, (float)ant, rs1), 0.f));
      sum = fmaxf(dap - dan + MARGIN_F, 0.f);
      cnt = 1.f;
    }
  }
  #pragma unroll
  for (int off = 32; off > 0; off >>= 1) {
    sum += __shfl_xor(sum, off);
    cnt += __shfl_xor(cnt, off);
  }
  int wv = tid >> 6;
  if ((tid & 63) == 0) { ssum[wv] = sum; scnt[wv] = cnt; }
  __syncthreads();
  if (tid == 0) {
    blk_sum[blockIdx.x] = ssum[0] + ssum[1] + ssum[2] + ssum[3];
    blk_cnt[blockIdx.x] = scnt[0] + scnt[1] + scnt[2] + scnt[3];
  }
}

// ---------------- K3b: final scalar over 64 block results ----------------
__global__ __launch_bounds__(64) void finalize_b_k(
    const float* __restrict__ blk_sum, const float* __restrict__ blk_cnt,
    float* __restrict__ out)
{
  int l = threadIdx.x;
  float s = blk_sum[l], c = blk_cnt[l];
  #pragma unroll
  for (int off = 32; off > 0; off >>= 1) {
    s += __shfl_xor(s, off);
    c += __shfl_xor(c, off);
  }
  if (l == 0) out[0] = (c > 0.f) ? (s / c) : 0.f;
}

extern "C" void kernel_launch(void* const* d_in, const int* in_sizes, int n_in,
                              void* d_out, int out_size, void* d_ws, size_t ws_size,
                              hipStream_t stream)
{
  const float* emb = (const float*)d_in[0];
  const int*   lab = (const int*)d_in[1];
  float* out = (float*)d_out;
  float* ws  = (float*)d_ws;

  float*    sqv     = ws;                              // BN floats
  int*      ap_part = (int*)(sqv + BN);                // NPART*BN ints (2 MB)
  int*      an_part = ap_part + NPART * BN;            // NPART*BN ints (2 MB)
  float*    blk_sum = (float*)(an_part + NPART * BN);  // 64
  float*    blk_cnt = blk_sum + 64;                    // 64
  unsigned* LP      = (unsigned*)(blk_cnt + 64);       // 2048 u32 (8 KB)
  char*     EnQ     = (char*)(LP + 2048);              // BN*DIM i8, k-major (~1 MB)

  norm_cvt_k<<<dim3(BN / 4), 256, 0, stream>>>(emb, lab, sqv, (unsigned short*)EnQ, LP);
  tri_gram_mine_k<<<dim3(NTILE), 256, 0, stream>>>(EnQ, lab, LP, ap_part, an_part);
  finalize_a_k<<<dim3(NRB), 256, 0, stream>>>(ap_part, an_part, sqv, blk_sum, blk_cnt);
  finalize_b_k<<<dim3(1), 64, 0, stream>>>(blk_sum, blk_cnt, out);
}